// Round 5
// baseline (255.613 us; speedup 1.0000x reference)
//
#include <hip/hip_runtime.h>
#include <math.h>

// Problem constants (from reference setup_inputs)
#define B_      8
#define F_      64        // features
#define HW_     65536     // 256*256 pixels
#define NSEG    33        // N_OBJECTS + 1
#define NOBJ    32
#define FPB     4         // features per segmax block (1 per wave)
#define FGRP    (F_ / FPB)       // 16 feature groups
#define SLICES  32        // pixel slices per batch
#define PIXB    (HW_ / SLICES)   // 2048 pixels per block
#define ENC_NEG_INF 0x007FFFFFu  // monotonic encoding of -inf

// Monotonic order-preserving float->uint encoding: unsigned max == float max.
__device__ __forceinline__ unsigned enc_f(float x) {
    unsigned u = __float_as_uint(x);
    return u ^ ((unsigned)((int)u >> 31) | 0x80000000u);
}
__device__ __forceinline__ float dec_f(unsigned e) {
    unsigned x = (e & 0x80000000u) ? (e ^ 0x80000000u) : ~e;
    return __uint_as_float(x);
}

// d_ws layout: float part[b][slice][NSEG][F_] = 8*32*33*64 floats = 2.16 MB.
// Every slot written unconditionally by exactly one block -> poison harmless.

// segmax: grid = 8 b * 16 fgroup * 32 slice = 4096 blocks, 256 thr (4 waves).
// One feature per wave. LDS slots acc[wave][seg][lane&31] = 16.9 KB/block ->
// 8 blocks/CU by LDS; __launch_bounds__(256,8) caps VGPRs so waves, not
// registers, bind. Slot shared by the wave's two lane-halves; ds_max is
// atomic, so a same-address pair inside one instr just micro-serializes
// (p ~ 1/33). Fire-and-forget: no dependent LDS read in the stream loop.
__global__ __launch_bounds__(256, 8) void segmax_kernel(
        const float* __restrict__ enc, const int* __restrict__ masks,
        float* __restrict__ part) {
    __shared__ unsigned acc[FPB * NSEG * 32];   // 16,896 B
    const int tid = threadIdx.x;
    const int blk = blockIdx.x;
    const int b     = blk >> 9;          // 16 fg * 32 slices = 512
    const int fg    = (blk >> 5) & 15;
    const int slice = blk & 31;

    for (int i = tid; i < FPB * NSEG * 32; i += 256) acc[i] = ENC_NEG_INF;
    __syncthreads();

    const int fl   = tid >> 6;    // wave id = feature within group: 0..3
    const int lane = tid & 63;
    unsigned* a = acc + fl * (NSEG * 32) + (lane & 31);   // + id*32 per element

    const float4* ep = (const float4*)(enc + ((size_t)(b * F_ + fg * FPB + fl)) * HW_
                                       + slice * PIXB) + lane;
    const int4*   mp = (const int4*)(masks + (size_t)b * HW_ + slice * PIXB) + lane;

    #pragma unroll 4
    for (int c = 0; c < PIXB / 256; ++c) {     // 8 iters, 256 pixels each
        float4 v  = ep[c * 64];
        int4   id = mp[c * 64];
        atomicMax(a + id.x * 32, enc_f(v.x));  // ds_max_u32, no return
        atomicMax(a + id.y * 32, enc_f(v.y));
        atomicMax(a + id.z * 32, enc_f(v.z));
        atomicMax(a + id.w * 32, enc_f(v.w));
    }
    __syncthreads();

    // Reduce 32 slot-copies per (f_local, seg); decode; write slice partial.
    float* dst = part + (((size_t)b * SLICES + slice) * NSEG) * F_;
    for (int cell = tid; cell < FPB * NSEG; cell += 256) {
        int f = cell & 3, s = cell >> 2;
        const unsigned* row = acc + f * (NSEG * 32) + s * 32;
        unsigned m = ENC_NEG_INF;
        #pragma unroll
        for (int k = 0; k < 32; k += 4) {
            uint4 q = *(const uint4*)(row + k);
            unsigned m1 = q.x > q.y ? q.x : q.y;
            unsigned m2 = q.z > q.w ? q.z : q.w;
            unsigned m3 = m1 > m2 ? m1 : m2;
            m = m > m3 ? m : m3;
        }
        dst[s * F_ + fg * FPB + f] = dec_f(m);
    }
}

// mlp: grid = 8 b * 4 i-tiles = 32 blocks. Reduces the 32 slice partials,
// writes vectors, then h = A_i + B_j + b1, out = sigmoid(h@W2 + b2),
// connections[b][c][j][i] = out[i][j][c]. All weights staged in LDS.
__global__ __launch_bounds__(256) void mlp_kernel(
        const float* __restrict__ part,
        const float* __restrict__ W1, const float* __restrict__ b1,
        const float* __restrict__ W2, const float* __restrict__ b2,
        float* __restrict__ out_vec, float* __restrict__ out_conn) {
    const int b   = blockIdx.x >> 2;
    const int it  = blockIdx.x & 3;          // i-tile: i = it*8 .. it*8+7
    const int tid = threadIdx.x;
    __shared__ float v[NOBJ * 65];           // [obj][f], pad 65 kills i-aliasing
    __shared__ float w1s[2 * F_ * 32];       // [d][k], 16 KB
    __shared__ float w2s[32 * 4];
    __shared__ float b1s[32];
    __shared__ float Am[8 * 36];             // [i_loc][k], pad 36 (f4-aligned)
    __shared__ float Bm[NOBJ * 36];

    for (int i = tid; i < 2 * F_ * 32 / 4; i += 256)
        ((float4*)w1s)[i] = ((const float4*)W1)[i];
    if (tid < 32) { w2s[tid*4+0]=W2[tid*4+0]; w2s[tid*4+1]=W2[tid*4+1];
                    w2s[tid*4+2]=W2[tid*4+2]; w2s[tid*4+3]=W2[tid*4+3];
                    b1s[tid] = b1[tid]; }

    // Slice-reduce: cells (s,f) for s=1..32, f=0..63. Coalesced over f.
    for (int cell = tid; cell < NOBJ * F_; cell += 256) {
        int s = (cell >> 6) + 1, f = cell & 63;
        float m = -INFINITY;
        #pragma unroll 8
        for (int sl = 0; sl < SLICES; ++sl)
            m = fmaxf(m, part[(((size_t)b * SLICES + sl) * NSEG + s) * F_ + f]);
        v[(s - 1) * 65 + f] = m;
        if (it == 0) out_vec[b * NOBJ * F_ + cell] = m;
    }
    __syncthreads();

    // 1280 length-64 dots as 320 float4-dots: d<64 -> Am (8 i_loc x 8 kg),
    // d>=64 -> Bm (32 j x 8 kg). Broadcast-friendly LDS access.
    for (int d = tid; d < 320; d += 256) {
        int kg, obj, half;
        if (d < 64) { half = 0; obj = it * 8 + (d >> 3); kg = d & 7; }
        else        { half = 1; obj = (d - 64) >> 3;     kg = d & 7; }
        const float* vv = v + obj * 65;
        const float* w  = w1s + half * (F_ * 32) + kg * 4;
        float4 s4 = {0.f, 0.f, 0.f, 0.f};
        #pragma unroll
        for (int f = 0; f < F_; ++f) {
            float4 wf = *(const float4*)(w + f * 32);
            float x = vv[f];
            s4.x = fmaf(x, wf.x, s4.x); s4.y = fmaf(x, wf.y, s4.y);
            s4.z = fmaf(x, wf.z, s4.z); s4.w = fmaf(x, wf.w, s4.w);
        }
        if (half == 0) {
            float4 bb = *(const float4*)(b1s + kg * 4);
            s4.x += bb.x; s4.y += bb.y; s4.z += bb.z; s4.w += bb.w;
            *(float4*)(Am + (d >> 3) * 36 + kg * 4) = s4;
        } else {
            *(float4*)(Bm + obj * 36 + kg * 4) = s4;
        }
    }
    __syncthreads();

    // 256 (i,j) pairs: one per thread.
    {
        int i_loc = tid >> 5, j = tid & 31;
        float o0 = b2[0], o1 = b2[1], o2 = b2[2], o3 = b2[3];
        #pragma unroll
        for (int kg = 0; kg < 8; ++kg) {
            float4 ha = *(const float4*)(Am + i_loc * 36 + kg * 4);
            float4 hb = *(const float4*)(Bm + j * 36 + kg * 4);
            float h0 = ha.x + hb.x, h1 = ha.y + hb.y;
            float h2 = ha.z + hb.z, h3 = ha.w + hb.w;
            const float* w2 = w2s + kg * 16;
            o0 = fmaf(h0, w2[0],  fmaf(h1, w2[4],  fmaf(h2, w2[8],  fmaf(h3, w2[12], o0))));
            o1 = fmaf(h0, w2[1],  fmaf(h1, w2[5],  fmaf(h2, w2[9],  fmaf(h3, w2[13], o1))));
            o2 = fmaf(h0, w2[2],  fmaf(h1, w2[6],  fmaf(h2, w2[10], fmaf(h3, w2[14], o2))));
            o3 = fmaf(h0, w2[3],  fmaf(h1, w2[7],  fmaf(h2, w2[11], fmaf(h3, w2[15], o3))));
        }
        float* oc = out_conn + (size_t)b * 4 * NOBJ * NOBJ + j * NOBJ + (it * 8 + i_loc);
        oc[0 * NOBJ * NOBJ] = 1.f / (1.f + expf(-o0));
        oc[1 * NOBJ * NOBJ] = 1.f / (1.f + expf(-o1));
        oc[2 * NOBJ * NOBJ] = 1.f / (1.f + expf(-o2));
        oc[3 * NOBJ * NOBJ] = 1.f / (1.f + expf(-o3));
    }
}

extern "C" void kernel_launch(void* const* d_in, const int* in_sizes, int n_in,
                              void* d_out, int out_size, void* d_ws, size_t ws_size,
                              hipStream_t stream) {
    const float* enc   = (const float*)d_in[0];
    const int*   masks = (const int*)  d_in[1];
    const float* W1    = (const float*)d_in[2];
    const float* b1    = (const float*)d_in[3];
    const float* W2    = (const float*)d_in[4];
    const float* b2    = (const float*)d_in[5];

    float* out_vec  = (float*)d_out;                 // 8*32*64 = 16384 floats
    float* out_conn = out_vec + B_ * NOBJ * F_;      // 8*4*32*32 = 32768 floats
    float* part     = (float*)d_ws;                  // 2.16 MB slice partials

    segmax_kernel<<<B_ * FGRP * SLICES, 256, 0, stream>>>(enc, masks, part);
    mlp_kernel<<<B_ * 4, 256, 0, stream>>>(part, W1, b1, W2, b2, out_vec, out_conn);
}

// Round 6
// 231.858 us; speedup vs baseline: 1.1025x; 1.1025x over previous
//
#include <hip/hip_runtime.h>
#include <math.h>

// Problem constants (from reference setup_inputs)
#define B_      8
#define F_      64        // features
#define HW_     65536     // 256*256 pixels
#define NSEG    33        // N_OBJECTS + 1
#define NOBJ    32
#define SLICES  128       // pixel slices per batch
#define PXB     (HW_ / SLICES)   // 512 pixels per block
#define ENC_NEG_INF 0x007FFFFFu  // monotonic encoding of -inf

// Monotonic order-preserving float->uint encoding: unsigned max == float max.
__device__ __forceinline__ unsigned enc_f(float x) {
    unsigned u = __float_as_uint(x);
    return u ^ ((unsigned)((int)u >> 31) | 0x80000000u);
}
__device__ __forceinline__ float dec_f(unsigned e) {
    unsigned x = (e & 0x80000000u) ? (e ^ 0x80000000u) : ~e;
    return __uint_as_float(x);
}

// gws layout: unsigned gws[b][32][64] (seg-1, f) = 16384 words = 64 KB.
// Poisoned each call -> re-init every launch.
__global__ void init_ws(unsigned* __restrict__ gws) {
    int i = blockIdx.x * blockDim.x + threadIdx.x;
    gws[i] = ENC_NEG_INF;   // grid sized exactly
}

// segmax: grid = 8 b * 128 slices = 1024 blocks (4/CU), 256 thr (4 waves).
// Block covers ALL 64 features of a 512-pixel slice: mask ids load once into
// registers (2 int4/lane) and are reused for 16 features per wave. LDS
// acc[64][33] = 8.4 KB; feature rows are wave-disjoint (wave w owns f in
// [16w,16w+16)), so atomics contend only within one wave-instruction
// (~2 lanes/segment avg, ~5 extra cyc/instr — R1-measured rate). DS+VALU
// both fit well under the 52k-cycle/CU HBM stream -> memory-bound.
__global__ __launch_bounds__(256, 4) void segmax_kernel(
        const float* __restrict__ enc, const int* __restrict__ masks,
        unsigned* __restrict__ gws) {
    __shared__ unsigned acc[F_ * NSEG];   // 8448 B
    const int tid   = threadIdx.x;
    const int b     = blockIdx.x >> 7;
    const int slice = blockIdx.x & 127;

    for (int i = tid; i < F_ * NSEG; i += 256) acc[i] = ENC_NEG_INF;

    const int wave = tid >> 6;    // owns features wave*16 .. wave*16+15
    const int lane = tid & 63;

    // Mask ids for this slice, register-cached, reused across 16 features.
    const int4* mp = (const int4*)(masks + (size_t)b * HW_ + slice * PXB);
    int4 id0 = mp[lane];          // pixels 4*lane   .. 4*lane+3
    int4 id1 = mp[lane + 64];     // pixels 256+4*lane .. +3
    __syncthreads();

    const float* ebase = enc + ((size_t)(b * F_ + wave * 16)) * HW_ + slice * PXB;
    #pragma unroll 4
    for (int fo = 0; fo < 16; ++fo) {
        const float4* ep = (const float4*)(ebase + (size_t)fo * HW_);
        float4 v0 = ep[lane];
        float4 v1 = ep[lane + 64];
        unsigned* a = acc + (wave * 16 + fo) * NSEG;
        atomicMax(a + id0.x, enc_f(v0.x));   // fire-and-forget ds_max_u32
        atomicMax(a + id0.y, enc_f(v0.y));
        atomicMax(a + id0.z, enc_f(v0.z));
        atomicMax(a + id0.w, enc_f(v0.w));
        atomicMax(a + id1.x, enc_f(v1.x));
        atomicMax(a + id1.y, enc_f(v1.y));
        atomicMax(a + id1.z, enc_f(v1.z));
        atomicMax(a + id1.w, enc_f(v1.w));
    }
    __syncthreads();

    // Read-filtered global flush (segs 1..32 only). Stale filter reads only
    // cause redundant atomics; atomicMax keeps it correct. ~5 winners/cell
    // across 128 blocks -> ~80k global atomics total.
    unsigned* gb = gws + b * (NOBJ * F_);
    for (int cell = tid; cell < NOBJ * F_; cell += 256) {
        int s = (cell >> 6) + 1, f = cell & 63;
        unsigned val = acc[f * NSEG + s];
        if (val > gb[cell]) atomicMax(gb + cell, val);
    }
}

// mlp: grid = 8 b * 4 i-tiles = 32 blocks. Decodes vectors from gws (64 KB,
// L2-hot), writes vectors, then h = A_i + B_j + b1, out = sigmoid(h@W2+b2),
// connections[b][c][j][i] = out[i][j][c]. All weights staged in LDS.
__global__ __launch_bounds__(256) void mlp_kernel(
        const unsigned* __restrict__ gws,
        const float* __restrict__ W1, const float* __restrict__ b1,
        const float* __restrict__ W2, const float* __restrict__ b2,
        float* __restrict__ out_vec, float* __restrict__ out_conn) {
    const int b   = blockIdx.x >> 2;
    const int it  = blockIdx.x & 3;          // i-tile: i = it*8 .. it*8+7
    const int tid = threadIdx.x;
    __shared__ float v[NOBJ * 65];           // [obj][f], pad 65 kills aliasing
    __shared__ float w1s[2 * F_ * 32];       // [d][k], 16 KB
    __shared__ float w2s[32 * 4];
    __shared__ float b1s[32];
    __shared__ float Am[8 * 36];             // [i_loc][k], pad 36 (f4-aligned)
    __shared__ float Bm[NOBJ * 36];

    for (int i = tid; i < 2 * F_ * 32 / 4; i += 256)
        ((float4*)w1s)[i] = ((const float4*)W1)[i];
    if (tid < 32) { w2s[tid*4+0]=W2[tid*4+0]; w2s[tid*4+1]=W2[tid*4+1];
                    w2s[tid*4+2]=W2[tid*4+2]; w2s[tid*4+3]=W2[tid*4+3];
                    b1s[tid] = b1[tid]; }

    // Decode vectors. gws cell = (s-1)*64 + f, matching out_vec layout.
    for (int cell = tid; cell < NOBJ * F_; cell += 256) {
        float m = dec_f(gws[b * (NOBJ * F_) + cell]);
        v[(cell >> 6) * 65 + (cell & 63)] = m;
        if (it == 0) out_vec[b * (NOBJ * F_) + cell] = m;
    }
    __syncthreads();

    // 1280 length-64 dots as 320 float4-dots: d<64 -> Am (8 i_loc x 8 kg),
    // d>=64 -> Bm (32 j x 8 kg). Broadcast-friendly LDS access.
    for (int d = tid; d < 320; d += 256) {
        int kg, obj, half;
        if (d < 64) { half = 0; obj = it * 8 + (d >> 3); kg = d & 7; }
        else        { half = 1; obj = (d - 64) >> 3;     kg = d & 7; }
        const float* vv = v + obj * 65;
        const float* w  = w1s + half * (F_ * 32) + kg * 4;
        float4 s4 = {0.f, 0.f, 0.f, 0.f};
        #pragma unroll
        for (int f = 0; f < F_; ++f) {
            float4 wf = *(const float4*)(w + f * 32);
            float x = vv[f];
            s4.x = fmaf(x, wf.x, s4.x); s4.y = fmaf(x, wf.y, s4.y);
            s4.z = fmaf(x, wf.z, s4.z); s4.w = fmaf(x, wf.w, s4.w);
        }
        if (half == 0) {
            float4 bb = *(const float4*)(b1s + kg * 4);
            s4.x += bb.x; s4.y += bb.y; s4.z += bb.z; s4.w += bb.w;
            *(float4*)(Am + (d >> 3) * 36 + kg * 4) = s4;
        } else {
            *(float4*)(Bm + obj * 36 + kg * 4) = s4;
        }
    }
    __syncthreads();

    // 256 (i,j) pairs: one per thread.
    {
        int i_loc = tid >> 5, j = tid & 31;
        float o0 = b2[0], o1 = b2[1], o2 = b2[2], o3 = b2[3];
        #pragma unroll
        for (int kg = 0; kg < 8; ++kg) {
            float4 ha = *(const float4*)(Am + i_loc * 36 + kg * 4);
            float4 hb = *(const float4*)(Bm + j * 36 + kg * 4);
            float h0 = ha.x + hb.x, h1 = ha.y + hb.y;
            float h2 = ha.z + hb.z, h3 = ha.w + hb.w;
            const float* w2 = w2s + kg * 16;
            o0 = fmaf(h0, w2[0],  fmaf(h1, w2[4],  fmaf(h2, w2[8],  fmaf(h3, w2[12], o0))));
            o1 = fmaf(h0, w2[1],  fmaf(h1, w2[5],  fmaf(h2, w2[9],  fmaf(h3, w2[13], o1))));
            o2 = fmaf(h0, w2[2],  fmaf(h1, w2[6],  fmaf(h2, w2[10], fmaf(h3, w2[14], o2))));
            o3 = fmaf(h0, w2[3],  fmaf(h1, w2[7],  fmaf(h2, w2[11], fmaf(h3, w2[15], o3))));
        }
        float* oc = out_conn + (size_t)b * 4 * NOBJ * NOBJ + j * NOBJ + (it * 8 + i_loc);
        oc[0 * NOBJ * NOBJ] = 1.f / (1.f + expf(-o0));
        oc[1 * NOBJ * NOBJ] = 1.f / (1.f + expf(-o1));
        oc[2 * NOBJ * NOBJ] = 1.f / (1.f + expf(-o2));
        oc[3 * NOBJ * NOBJ] = 1.f / (1.f + expf(-o3));
    }
}

extern "C" void kernel_launch(void* const* d_in, const int* in_sizes, int n_in,
                              void* d_out, int out_size, void* d_ws, size_t ws_size,
                              hipStream_t stream) {
    const float* enc   = (const float*)d_in[0];
    const int*   masks = (const int*)  d_in[1];
    const float* W1    = (const float*)d_in[2];
    const float* b1    = (const float*)d_in[3];
    const float* W2    = (const float*)d_in[4];
    const float* b2    = (const float*)d_in[5];

    float* out_vec  = (float*)d_out;                 // 8*32*64 = 16384 floats
    float* out_conn = out_vec + B_ * NOBJ * F_;      // 8*4*32*32 = 32768 floats
    unsigned* gws   = (unsigned*)d_ws;               // 8*32*64 uints = 64 KB

    init_ws<<<B_ * NOBJ * F_ / 256, 256, 0, stream>>>(gws);
    segmax_kernel<<<B_ * SLICES, 256, 0, stream>>>(enc, masks, gws);
    mlp_kernel<<<B_ * 4, 256, 0, stream>>>(gws, W1, b1, W2, b2, out_vec, out_conn);
}

// Round 7
// 223.367 us; speedup vs baseline: 1.1444x; 1.0380x over previous
//
#include <hip/hip_runtime.h>
#include <math.h>

// Problem constants (from reference setup_inputs)
#define B_      8
#define F_      64        // features
#define HW_     65536     // 256*256 pixels
#define NSEG    33        // N_OBJECTS + 1
#define NOBJ    32
#define FPB     8         // features per segmax block
#define FGRP    (F_ / FPB)       // 8 feature groups
#define SLICES  16        // pixel slices per batch
#define PIXB    (HW_ / SLICES)   // 4096 pixels per block
#define ENC_NEG_INF 0x007FFFFFu  // monotonic encoding of -inf

// Monotonic order-preserving float->uint encoding: unsigned max == float max.
__device__ __forceinline__ unsigned enc_f(float x) {
    unsigned u = __float_as_uint(x);
    return u ^ ((unsigned)((int)u >> 31) | 0x80000000u);
}
__device__ __forceinline__ float dec_f(unsigned e) {
    unsigned x = (e & 0x80000000u) ? (e ^ 0x80000000u) : ~e;
    return __uint_as_float(x);
}

// gws layout: unsigned gws[b][32][64] (seg-1, f) = 16384 words = 64 KB.
// Poisoned each call -> re-init every launch.
__global__ void init_ws(unsigned* __restrict__ gws) {
    gws[blockIdx.x * blockDim.x + threadIdx.x] = ENC_NEG_INF;
}

// segmax: grid = 8 b * 8 fg * 16 slices = 1024 blocks (4/CU by 33.8 KB LDS).
// Private-slot accumulators acc[fl][seg][l] (fl=tid>>5, l=tid&31): bank = l
// for any seg, exactly one owner per slot -> zero same-address serialization,
// zero bank conflicts beyond the wave64 2-pass minimum (free, m136).
// Update = fire-and-forget ds_max_u32 (no dependent LDS read).
// Loads tile-batched: 8 float4 + 8 int4 issued back-to-back before the
// atomic burst -> 16 VMEM in flight per wave to cover HBM/L3 latency.
// __launch_bounds__(256,4): VGPR cap 128 (est. ~90 live) so LDS, not
// registers, sets the 4-block/CU occupancy.
__global__ __launch_bounds__(256, 4) void segmax_kernel(
        const float* __restrict__ enc, const int* __restrict__ masks,
        unsigned* __restrict__ gws) {
    __shared__ unsigned acc[FPB * NSEG * 32];   // 33,792 B
    const int tid   = threadIdx.x;
    const int b     = blockIdx.x >> 7;          // 8 fg * 16 slices = 128
    const int fg    = (blockIdx.x >> 4) & 7;
    const int slice = blockIdx.x & 15;

    for (int i = tid; i < FPB * NSEG * 32; i += 256) acc[i] = ENC_NEG_INF;
    __syncthreads();

    const int fl = tid >> 5;      // feature within group: 0..7 (32 thr each)
    const int l  = tid & 31;      // private slot
    unsigned* a = acc + fl * (NSEG * 32) + l;   // + id*32 per element

    const float4* ep = (const float4*)(enc + ((size_t)(b * F_ + fg * FPB + fl)) * HW_
                                       + slice * PIXB) + l;
    const int4*   mp = (const int4*)(masks + (size_t)b * HW_ + slice * PIXB) + l;

    // 1024 float4s per feature / 32 threads = 32 per thread, in 4 tiles of 8.
    for (int t = 0; t < 4; ++t) {
        float4 v[8]; int4 id[8];
        #pragma unroll
        for (int u = 0; u < 8; ++u) {
            v[u]  = ep[(t * 8 + u) * 32];
            id[u] = mp[(t * 8 + u) * 32];
        }
        #pragma unroll
        for (int u = 0; u < 8; ++u) {
            atomicMax(a + id[u].x * 32, enc_f(v[u].x));  // ds_max_u32
            atomicMax(a + id[u].y * 32, enc_f(v[u].y));
            atomicMax(a + id[u].z * 32, enc_f(v[u].z));
            atomicMax(a + id[u].w * 32, enc_f(v[u].w));
        }
    }
    __syncthreads();

    // Slot-reduce + read-filtered global flush (segs 1..32; one cell/thread).
    // Stale filter reads can only be smaller than the committed value ->
    // worst case a redundant atomic; atomicMax keeps it correct.
    const int fl2 = tid >> 5;            // feature row 0..7
    const int s   = (tid & 31) + 1;      // segment 1..32
    const unsigned* row = acc + fl2 * (NSEG * 32) + s * 32;
    unsigned m = ENC_NEG_INF;
    #pragma unroll
    for (int k = 0; k < 32; k += 4) {
        uint4 q = *(const uint4*)(row + k);
        unsigned m1 = q.x > q.y ? q.x : q.y;
        unsigned m2 = q.z > q.w ? q.z : q.w;
        unsigned m3 = m1 > m2 ? m1 : m2;
        m = m > m3 ? m : m3;
    }
    unsigned* gb = gws + b * (NOBJ * F_) + (s - 1) * F_ + (fg * FPB + fl2);
    if (m > *gb) atomicMax(gb, m);
}

// mlp: grid = 8 b * 4 i-tiles = 32 blocks. Decodes vectors from gws (64 KB,
// L2-hot), writes vectors, then h = A_i + B_j + b1, out = sigmoid(h@W2+b2),
// connections[b][c][j][i] = out[i][j][c]. All weights staged in LDS.
__global__ __launch_bounds__(256) void mlp_kernel(
        const unsigned* __restrict__ gws,
        const float* __restrict__ W1, const float* __restrict__ b1,
        const float* __restrict__ W2, const float* __restrict__ b2,
        float* __restrict__ out_vec, float* __restrict__ out_conn) {
    const int b   = blockIdx.x >> 2;
    const int it  = blockIdx.x & 3;          // i-tile: i = it*8 .. it*8+7
    const int tid = threadIdx.x;
    __shared__ float v[NOBJ * 65];           // [obj][f], pad 65 kills aliasing
    __shared__ float w1s[2 * F_ * 32];       // [d][k], 16 KB
    __shared__ float w2s[32 * 4];
    __shared__ float b1s[32];
    __shared__ float Am[8 * 36];             // [i_loc][k], pad 36 (f4-aligned)
    __shared__ float Bm[NOBJ * 36];

    for (int i = tid; i < 2 * F_ * 32 / 4; i += 256)
        ((float4*)w1s)[i] = ((const float4*)W1)[i];
    if (tid < 32) { w2s[tid*4+0]=W2[tid*4+0]; w2s[tid*4+1]=W2[tid*4+1];
                    w2s[tid*4+2]=W2[tid*4+2]; w2s[tid*4+3]=W2[tid*4+3];
                    b1s[tid] = b1[tid]; }

    // Decode vectors. gws cell = (s-1)*64 + f, matching out_vec layout.
    for (int cell = tid; cell < NOBJ * F_; cell += 256) {
        float m = dec_f(gws[b * (NOBJ * F_) + cell]);
        v[(cell >> 6) * 65 + (cell & 63)] = m;
        if (it == 0) out_vec[b * (NOBJ * F_) + cell] = m;
    }
    __syncthreads();

    // 1280 length-64 dots as 320 float4-dots: d<64 -> Am (8 i_loc x 8 kg),
    // d>=64 -> Bm (32 j x 8 kg). Broadcast-friendly LDS access.
    for (int d = tid; d < 320; d += 256) {
        int kg, obj, half;
        if (d < 64) { half = 0; obj = it * 8 + (d >> 3); kg = d & 7; }
        else        { half = 1; obj = (d - 64) >> 3;     kg = d & 7; }
        const float* vv = v + obj * 65;
        const float* w  = w1s + half * (F_ * 32) + kg * 4;
        float4 s4 = {0.f, 0.f, 0.f, 0.f};
        #pragma unroll
        for (int f = 0; f < F_; ++f) {
            float4 wf = *(const float4*)(w + f * 32);
            float x = vv[f];
            s4.x = fmaf(x, wf.x, s4.x); s4.y = fmaf(x, wf.y, s4.y);
            s4.z = fmaf(x, wf.z, s4.z); s4.w = fmaf(x, wf.w, s4.w);
        }
        if (half == 0) {
            float4 bb = *(const float4*)(b1s + kg * 4);
            s4.x += bb.x; s4.y += bb.y; s4.z += bb.z; s4.w += bb.w;
            *(float4*)(Am + (d >> 3) * 36 + kg * 4) = s4;
        } else {
            *(float4*)(Bm + obj * 36 + kg * 4) = s4;
        }
    }
    __syncthreads();

    // 256 (i,j) pairs: one per thread.
    {
        int i_loc = tid >> 5, j = tid & 31;
        float o0 = b2[0], o1 = b2[1], o2 = b2[2], o3 = b2[3];
        #pragma unroll
        for (int kg = 0; kg < 8; ++kg) {
            float4 ha = *(const float4*)(Am + i_loc * 36 + kg * 4);
            float4 hb = *(const float4*)(Bm + j * 36 + kg * 4);
            float h0 = ha.x + hb.x, h1 = ha.y + hb.y;
            float h2 = ha.z + hb.z, h3 = ha.w + hb.w;
            const float* w2 = w2s + kg * 16;
            o0 = fmaf(h0, w2[0],  fmaf(h1, w2[4],  fmaf(h2, w2[8],  fmaf(h3, w2[12], o0))));
            o1 = fmaf(h0, w2[1],  fmaf(h1, w2[5],  fmaf(h2, w2[9],  fmaf(h3, w2[13], o1))));
            o2 = fmaf(h0, w2[2],  fmaf(h1, w2[6],  fmaf(h2, w2[10], fmaf(h3, w2[14], o2))));
            o3 = fmaf(h0, w2[3],  fmaf(h1, w2[7],  fmaf(h2, w2[11], fmaf(h3, w2[15], o3))));
        }
        float* oc = out_conn + (size_t)b * 4 * NOBJ * NOBJ + j * NOBJ + (it * 8 + i_loc);
        oc[0 * NOBJ * NOBJ] = 1.f / (1.f + expf(-o0));
        oc[1 * NOBJ * NOBJ] = 1.f / (1.f + expf(-o1));
        oc[2 * NOBJ * NOBJ] = 1.f / (1.f + expf(-o2));
        oc[3 * NOBJ * NOBJ] = 1.f / (1.f + expf(-o3));
    }
}

extern "C" void kernel_launch(void* const* d_in, const int* in_sizes, int n_in,
                              void* d_out, int out_size, void* d_ws, size_t ws_size,
                              hipStream_t stream) {
    const float* enc   = (const float*)d_in[0];
    const int*   masks = (const int*)  d_in[1];
    const float* W1    = (const float*)d_in[2];
    const float* b1    = (const float*)d_in[3];
    const float* W2    = (const float*)d_in[4];
    const float* b2    = (const float*)d_in[5];

    float* out_vec  = (float*)d_out;                 // 8*32*64 = 16384 floats
    float* out_conn = out_vec + B_ * NOBJ * F_;      // 8*4*32*32 = 32768 floats
    unsigned* gws   = (unsigned*)d_ws;               // 8*32*64 uints = 64 KB

    init_ws<<<B_ * NOBJ * F_ / 256, 256, 0, stream>>>(gws);
    segmax_kernel<<<B_ * FGRP * SLICES, 256, 0, stream>>>(enc, masks, gws);
    mlp_kernel<<<B_ * 4, 256, 0, stream>>>(gws, W1, b1, W2, b2, out_vec, out_conn);
}

// Round 8
// 219.335 us; speedup vs baseline: 1.1654x; 1.0184x over previous
//
#include <hip/hip_runtime.h>
#include <math.h>

// Problem constants (from reference setup_inputs)
#define B_      8
#define F_      64        // features
#define HW_     65536     // 256*256 pixels
#define NSEG    33        // N_OBJECTS + 1
#define NOBJ    32
#define FPB     8         // features per segmax block
#define SLICES  8         // pixel slices per batch (R3 champion config)
#define PIXB    (HW_ / SLICES)   // 8192 pixels per block
#define ENC_NEG_INF 0x007FFFFFu  // monotonic encoding of -inf

// Monotonic order-preserving float->uint encoding: unsigned max == float max.
__device__ __forceinline__ unsigned enc_f(float x) {
    unsigned u = __float_as_uint(x);
    return u ^ ((unsigned)((int)u >> 31) | 0x80000000u);
}
__device__ __forceinline__ float dec_f(unsigned e) {
    unsigned x = (e & 0x80000000u) ? (e ^ 0x80000000u) : ~e;
    return __uint_as_float(x);
}

// d_ws layout: float part[b][slice][NSEG][F_] = 8*8*33*64 floats = 540,672 B.
// Every slot written unconditionally by exactly one block -> no init pass,
// no atomics, poisoned ws harmless. Only 2 dispatches total.

// segmax: grid = 8 b * 8 fgroup * 8 slice = 512 blocks, 256 threads.
// Per-thread-private LDS slots acc[f_local][seg][slot]: word index
// f*1056 + seg*32 + slot -> bank = slot for any seg: zero bank conflicts
// beyond the free wave64 2-pass; exactly one owner per slot -> zero
// same-address contention. Update = fire-and-forget ds_max_u32 on encoded
// floats: 1 DS op/element, no dependent LDS read, no lgkmcnt stall in the
// stream loop (the single delta vs the R3 champion's read-fmax-write).
__global__ __launch_bounds__(256) void segmax_kernel(
        const float* __restrict__ enc, const int* __restrict__ masks,
        float* __restrict__ part) {
    __shared__ unsigned acc[FPB * NSEG * 32];   // 33,792 B
    const int tid = threadIdx.x;
    const int blk = blockIdx.x;
    const int b     = blk >> 6;          // 8 fg * 8 slices = 64
    const int fg    = (blk >> 3) & 7;
    const int slice = blk & 7;

    for (int i = tid; i < FPB * NSEG * 32; i += 256) acc[i] = ENC_NEG_INF;
    __syncthreads();

    const int fl = tid >> 5;      // feature within group: 0..7
    const int l  = tid & 31;      // private slot
    unsigned* a = acc + fl * (NSEG * 32) + l;   // + id*32 per element

    const float4* ep = (const float4*)(enc + ((size_t)(b * F_ + fg * FPB + fl)) * HW_
                                       + slice * PIXB) + l;
    const int4*   mp = (const int4*)(masks + (size_t)b * HW_ + slice * PIXB) + l;

    #pragma unroll 8
    for (int c = 0; c < PIXB / 128; ++c) {     // 64 iters, 128 pixels each
        float4 v  = ep[c * 32];
        int4   id = mp[c * 32];
        atomicMax(a + id.x * 32, enc_f(v.x));  // ds_max_u32, fire-and-forget
        atomicMax(a + id.y * 32, enc_f(v.y));
        atomicMax(a + id.z * 32, enc_f(v.z));
        atomicMax(a + id.w * 32, enc_f(v.w));
    }
    __syncthreads();

    // Reduce 32 slot-copies per (f_local, seg); decode; write slice partial.
    float* dst = part + (((size_t)b * SLICES + slice) * NSEG) * F_;
    for (int cell = tid; cell < FPB * NSEG; cell += 256) {
        int f = cell & 7, s = cell >> 3;
        const unsigned* row = acc + f * (NSEG * 32) + s * 32;
        unsigned m = ENC_NEG_INF;
        #pragma unroll
        for (int k = 0; k < 32; k += 4) {
            uint4 q = *(const uint4*)(row + k);
            unsigned m1 = q.x > q.y ? q.x : q.y;
            unsigned m2 = q.z > q.w ? q.z : q.w;
            unsigned m3 = m1 > m2 ? m1 : m2;
            m = m > m3 ? m : m3;
        }
        dst[s * F_ + fg * FPB + f] = dec_f(m);
    }
}

// mlp: grid = 8 b * 4 i-tiles = 32 blocks. Reduces the 8 slice partials,
// writes vectors, then h = A_i + B_j + b1, out = sigmoid(h@W2 + b2),
// connections[b][c][j][i] = out[i][j][c]. All weights staged in LDS.
__global__ __launch_bounds__(256) void mlp_kernel(
        const float* __restrict__ part,
        const float* __restrict__ W1, const float* __restrict__ b1,
        const float* __restrict__ W2, const float* __restrict__ b2,
        float* __restrict__ out_vec, float* __restrict__ out_conn) {
    const int b   = blockIdx.x >> 2;
    const int it  = blockIdx.x & 3;          // i-tile: i = it*8 .. it*8+7
    const int tid = threadIdx.x;
    __shared__ float v[NOBJ * 65];           // [obj][f], pad 65 kills aliasing
    __shared__ float w1s[2 * F_ * 32];       // [d][k], 16 KB
    __shared__ float w2s[32 * 4];
    __shared__ float b1s[32];
    __shared__ float Am[8 * 36];             // [i_loc][k], pad 36 (f4-aligned)
    __shared__ float Bm[NOBJ * 36];

    for (int i = tid; i < 2 * F_ * 32 / 4; i += 256)
        ((float4*)w1s)[i] = ((const float4*)W1)[i];
    if (tid < 32) { w2s[tid*4+0]=W2[tid*4+0]; w2s[tid*4+1]=W2[tid*4+1];
                    w2s[tid*4+2]=W2[tid*4+2]; w2s[tid*4+3]=W2[tid*4+3];
                    b1s[tid] = b1[tid]; }

    // Slice-reduce: cells (s,f) for s=1..32, f=0..63. Coalesced over f.
    for (int cell = tid; cell < NOBJ * F_; cell += 256) {
        int s = (cell >> 6) + 1, f = cell & 63;
        float m = -INFINITY;
        #pragma unroll
        for (int sl = 0; sl < SLICES; ++sl)
            m = fmaxf(m, part[(((size_t)b * SLICES + sl) * NSEG + s) * F_ + f]);
        v[(s - 1) * 65 + f] = m;
        if (it == 0) out_vec[b * NOBJ * F_ + cell] = m;
    }
    __syncthreads();

    // 1280 length-64 dots as 320 float4-dots: d<64 -> Am (8 i_loc x 8 kg),
    // d>=64 -> Bm (32 j x 8 kg). Broadcast-friendly LDS access.
    for (int d = tid; d < 320; d += 256) {
        int kg, obj, half;
        if (d < 64) { half = 0; obj = it * 8 + (d >> 3); kg = d & 7; }
        else        { half = 1; obj = (d - 64) >> 3;     kg = d & 7; }
        const float* vv = v + obj * 65;
        const float* w  = w1s + half * (F_ * 32) + kg * 4;
        float4 s4 = {0.f, 0.f, 0.f, 0.f};
        #pragma unroll
        for (int f = 0; f < F_; ++f) {
            float4 wf = *(const float4*)(w + f * 32);
            float x = vv[f];
            s4.x = fmaf(x, wf.x, s4.x); s4.y = fmaf(x, wf.y, s4.y);
            s4.z = fmaf(x, wf.z, s4.z); s4.w = fmaf(x, wf.w, s4.w);
        }
        if (half == 0) {
            float4 bb = *(const float4*)(b1s + kg * 4);
            s4.x += bb.x; s4.y += bb.y; s4.z += bb.z; s4.w += bb.w;
            *(float4*)(Am + (d >> 3) * 36 + kg * 4) = s4;
        } else {
            *(float4*)(Bm + obj * 36 + kg * 4) = s4;
        }
    }
    __syncthreads();

    // 256 (i,j) pairs: one per thread.
    {
        int i_loc = tid >> 5, j = tid & 31;
        float o0 = b2[0], o1 = b2[1], o2 = b2[2], o3 = b2[3];
        #pragma unroll
        for (int kg = 0; kg < 8; ++kg) {
            float4 ha = *(const float4*)(Am + i_loc * 36 + kg * 4);
            float4 hb = *(const float4*)(Bm + j * 36 + kg * 4);
            float h0 = ha.x + hb.x, h1 = ha.y + hb.y;
            float h2 = ha.z + hb.z, h3 = ha.w + hb.w;
            const float* w2 = w2s + kg * 16;
            o0 = fmaf(h0, w2[0],  fmaf(h1, w2[4],  fmaf(h2, w2[8],  fmaf(h3, w2[12], o0))));
            o1 = fmaf(h0, w2[1],  fmaf(h1, w2[5],  fmaf(h2, w2[9],  fmaf(h3, w2[13], o1))));
            o2 = fmaf(h0, w2[2],  fmaf(h1, w2[6],  fmaf(h2, w2[10], fmaf(h3, w2[14], o2))));
            o3 = fmaf(h0, w2[3],  fmaf(h1, w2[7],  fmaf(h2, w2[11], fmaf(h3, w2[15], o3))));
        }
        float* oc = out_conn + (size_t)b * 4 * NOBJ * NOBJ + j * NOBJ + (it * 8 + i_loc);
        oc[0 * NOBJ * NOBJ] = 1.f / (1.f + expf(-o0));
        oc[1 * NOBJ * NOBJ] = 1.f / (1.f + expf(-o1));
        oc[2 * NOBJ * NOBJ] = 1.f / (1.f + expf(-o2));
        oc[3 * NOBJ * NOBJ] = 1.f / (1.f + expf(-o3));
    }
}

extern "C" void kernel_launch(void* const* d_in, const int* in_sizes, int n_in,
                              void* d_out, int out_size, void* d_ws, size_t ws_size,
                              hipStream_t stream) {
    const float* enc   = (const float*)d_in[0];
    const int*   masks = (const int*)  d_in[1];
    const float* W1    = (const float*)d_in[2];
    const float* b1    = (const float*)d_in[3];
    const float* W2    = (const float*)d_in[4];
    const float* b2    = (const float*)d_in[5];

    float* out_vec  = (float*)d_out;                 // 8*32*64 = 16384 floats
    float* out_conn = out_vec + B_ * NOBJ * F_;      // 8*4*32*32 = 32768 floats
    float* part     = (float*)d_ws;                  // 540,672 B slice partials

    segmax_kernel<<<B_ * (F_ / FPB) * SLICES, 256, 0, stream>>>(enc, masks, part);
    mlp_kernel<<<B_ * 4, 256, 0, stream>>>(part, W1, b1, W2, b2, out_vec, out_conn);
}